// Round 11
// baseline (602.497 us; speedup 1.0000x reference)
//
#include <hip/hip_runtime.h>
#include <hip/hip_fp16.h>
#include <math.h>

typedef unsigned long long ull;

#define DIM  64
#define SPAN 256            // nodes per bucket (dst>>8)
#define SPAN_SHIFT 8
#define KMAX 512            // max buckets (N <= 131072); scan kernel width
#define CAP  6144           // LDS staging capacity per bucket (48 KB)

// ---------------- Kernel 1: per-node scores + fp16 x copy ------------------
// One wave per node. Block 0 also zeroes gcnt (hist runs after, stream order).
__global__ void score_kernel(const float* __restrict__ x,
                             const float* __restrict__ w_src,
                             const float* __restrict__ w_dst,
                             float* __restrict__ a_src,
                             float* __restrict__ a_dst,
                             __half* __restrict__ xh,
                             int* __restrict__ gcnt,
                             int N, int K) {
    if (blockIdx.x == 0) {
        for (int j = threadIdx.x; j < K; j += blockDim.x) gcnt[j] = 0;
    }
    int gid  = blockIdx.x * blockDim.x + threadIdx.x;
    int node = gid >> 6;
    int lane = threadIdx.x & 63;
    if (node >= N) return;
    float xv = x[(size_t)node * DIM + lane];
    xh[(size_t)node * DIM + lane] = __float2half_rn(xv);
    float s1 = xv * w_src[lane];
    float s2 = xv * w_dst[lane];
    #pragma unroll
    for (int off = 32; off > 0; off >>= 1) {
        s1 += __shfl_down(s1, off, 64);
        s2 += __shfl_down(s2, off, 64);
    }
    if (lane == 0) {
        a_src[node] = s1;
        a_dst[node] = s2;
    }
}

// ---------------- Kernel 2: histogram -> global bucket counts --------------
// LDS-private hist per block, one global atomicAdd per (block,bucket).
// int4-vectorized dst reads. Integer atomics => deterministic counts.
__global__ __launch_bounds__(1024) void hist_kernel(
        const int* __restrict__ dst, int* __restrict__ gcnt,
        int E, int N, int K) {
    __shared__ int lh[KMAX];
    int tid = threadIdx.x;
    for (int j = tid; j < K; j += blockDim.x) lh[j] = 0;
    __syncthreads();
    int gtid   = blockIdx.x * blockDim.x + tid;
    int stride = gridDim.x * blockDim.x;
    int EV = E >> 2;
    const int4* dst4 = (const int4*)dst;
    for (int i = gtid; i < EV; i += stride) {
        int4 t4 = dst4[i];
        unsigned t0 = (unsigned)t4.x; if (t0 >= (unsigned)N) t0 = 0;
        unsigned t1 = (unsigned)t4.y; if (t1 >= (unsigned)N) t1 = 0;
        unsigned t2 = (unsigned)t4.z; if (t2 >= (unsigned)N) t2 = 0;
        unsigned t3 = (unsigned)t4.w; if (t3 >= (unsigned)N) t3 = 0;
        atomicAdd(&lh[t0 >> SPAN_SHIFT], 1);
        atomicAdd(&lh[t1 >> SPAN_SHIFT], 1);
        atomicAdd(&lh[t2 >> SPAN_SHIFT], 1);
        atomicAdd(&lh[t3 >> SPAN_SHIFT], 1);
    }
    for (int e = (EV << 2) + gtid; e < E; e += stride) {     // tail
        unsigned t = (unsigned)dst[e];
        if (t >= (unsigned)N) t = 0;
        atomicAdd(&lh[t >> SPAN_SHIFT], 1);
    }
    __syncthreads();
    for (int j = tid; j < K; j += blockDim.x)
        if (lh[j]) atomicAdd(&gcnt[j], lh[j]);
}

// ---------------- Kernel 3: tiny scan (1 block) ----------------------------
// Exclusive scan of gcnt[K] -> gbase[0..K] (gbase[K]=E), init gcur.
__global__ __launch_bounds__(512) void scan_kernel(
        const int* __restrict__ gcnt, int* __restrict__ gbase,
        int* __restrict__ gcur, int K, int E) {
    __shared__ int buf[2][512];
    int tid = threadIdx.x;
    int v = (tid < K) ? gcnt[tid] : 0;
    int sel = 0;
    buf[0][tid] = v;
    __syncthreads();
    for (int off = 1; off < 512; off <<= 1) {
        int nsel = sel ^ 1;
        buf[nsel][tid] = buf[sel][tid] + ((tid >= off) ? buf[sel][tid - off] : 0);
        __syncthreads();
        sel = nsel;
    }
    if (tid < K) {
        int excl = buf[sel][tid] - v;
        gbase[tid] = excl;
        gcur[tid]  = excl;
    }
    if (tid == 511) gbase[K] = E;         // total == E (every edge counted)
}

// ---------------- Kernel 4: binpass — global atomic cursors ----------------
// 2 edges/thread, int2/float2 loads. pay = rec32<<32 | f32bits(a),
// rec32 = src<<8 | dst_local. Within-bucket order nondeterministic (fp32
// accumulation order downstream: error ~1e-6, absmax is fp16-dominated).
__global__ __launch_bounds__(256) void binpass_atomic(
        const float* __restrict__ ew,
        const int* __restrict__ src_idx,
        const int* __restrict__ dst_idx,
        const float* __restrict__ a_src,
        const float* __restrict__ a_dst,
        int* __restrict__ gcur,
        ull* __restrict__ pay,
        int E, int N) {
    int i  = blockIdx.x * blockDim.x + threadIdx.x;
    int e0 = i << 1;
    if (e0 >= E) return;
    if (e0 + 1 < E) {
        int2   s2 = ((const int2*)src_idx)[i];
        int2   t2 = ((const int2*)dst_idx)[i];
        float2 w2 = ((const float2*)ew)[i];
        unsigned s0 = (unsigned)s2.x; if (s0 >= (unsigned)N) s0 = 0;
        unsigned t0 = (unsigned)t2.x; if (t0 >= (unsigned)N) t0 = 0;
        unsigned s1 = (unsigned)s2.y; if (s1 >= (unsigned)N) s1 = 0;
        unsigned t1 = (unsigned)t2.y; if (t1 >= (unsigned)N) t1 = 0;
        float a0 = tanhf(a_src[s0] + a_dst[t0]) * w2.x;
        float a1 = tanhf(a_src[s1] + a_dst[t1]) * w2.y;
        int p0 = atomicAdd(&gcur[t0 >> SPAN_SHIFT], 1);
        int p1 = atomicAdd(&gcur[t1 >> SPAN_SHIFT], 1);
        unsigned r0 = (s0 << 8) | (t0 & (SPAN - 1u));
        unsigned r1 = (s1 << 8) | (t1 & (SPAN - 1u));
        pay[p0] = ((ull)r0 << 32) | (ull)__float_as_uint(a0);
        pay[p1] = ((ull)r1 << 32) | (ull)__float_as_uint(a1);
    } else {
        unsigned s0 = (unsigned)src_idx[e0]; if (s0 >= (unsigned)N) s0 = 0;
        unsigned t0 = (unsigned)dst_idx[e0]; if (t0 >= (unsigned)N) t0 = 0;
        float a0 = tanhf(a_src[s0] + a_dst[t0]) * ew[e0];
        int p0 = atomicAdd(&gcur[t0 >> SPAN_SHIFT], 1);
        unsigned r0 = (s0 << 8) | (t0 & (SPAN - 1u));
        pay[p0] = ((ull)r0 << 32) | (ull)__float_as_uint(a0);
    }
}

// ---------------- Kernel 5: fused per-bucket sort + gather -----------------
// Identical to the measured round-8 kernel (46.0 us) except bucket bounds
// come from gbase[b], gbase[b+1].
__global__ __launch_bounds__(1024) void sort_gather_kernel(
        const __half* __restrict__ xh,
        const float* __restrict__ x32,
        const ull* __restrict__ pay,
        const int* __restrict__ gbase,
        float* __restrict__ h,
        int N, int K, int E) {
    __shared__ ull srec[CAP];                     // 48 KB
    __shared__ unsigned short sidx[CAP];          // 12 KB
    __shared__ int hcnt[SPAN];
    __shared__ int hoff[2][SPAN];
    __shared__ int lcur[SPAN];
    __shared__ int nstart[SPAN];
    int tid = threadIdx.x;
    int b   = blockIdx.x;
    int bstart = gbase[b];
    int bend   = gbase[b + 1];
    int cnt = bend - bstart;

    if (cnt <= CAP) {
        // ---- stage + histogram ----
        if (tid < SPAN) hcnt[tid] = 0;
        __syncthreads();
        for (int i = tid; i < cnt; i += 1024) {
            ull r = pay[bstart + i];
            srec[i] = r;
            atomicAdd(&hcnt[(int)((r >> 32) & (SPAN - 1u))], 1);
        }
        __syncthreads();
        // ---- inclusive scan of hcnt[SPAN] ----
        int sel = 0;
        if (tid < SPAN) hoff[0][tid] = hcnt[tid];
        __syncthreads();
        for (int off = 1; off < SPAN; off <<= 1) {
            int nsel = sel ^ 1;
            if (tid < SPAN)
                hoff[nsel][tid] = hoff[sel][tid] +
                                  ((tid >= off) ? hoff[sel][tid - off] : 0);
            __syncthreads();
            sel = nsel;
        }
        if (tid < SPAN) {
            int excl = hoff[sel][tid] - hcnt[tid];
            nstart[tid] = excl;
            lcur[tid]   = excl;
        }
        __syncthreads();
        // ---- permute indices only (sidx), srec stays put ----
        for (int i = tid; i < cnt; i += 1024) {
            ull r = srec[i];
            int d = (int)((r >> 32) & (SPAN - 1u));
            int pos = atomicAdd(&lcur[d], 1);
            sidx[pos] = (unsigned short)i;
        }
        __syncthreads();
        // ---- gather: 4 nodes/wave, 4 edges/iter, 4 loads in flight -------
        int lane = tid & 63;
        int wave = tid >> 6;                      // 16 waves
        int grp  = lane >> 4;                     // node slot 0..3
        int sub  = lane & 15;                     // dim quad
        for (int d0 = (wave << 2); d0 < SPAN; d0 += 64) {
            int d = d0 + grp;
            int node = b * SPAN + d;
            int p  = nstart[d];
            int pe = p + hcnt[d];
            if (node >= N) pe = p;                // dead node: no work
            float ax = 0.f, ay = 0.f, az = 0.f, aw = 0.f;
            while (p + 4 <= pe) {
                ull r0 = srec[sidx[p]];
                ull r1 = srec[sidx[p + 1]];
                ull r2 = srec[sidx[p + 2]];
                ull r3 = srec[sidx[p + 3]];
                p += 4;
                unsigned s0 = (unsigned)(r0 >> 40); if (s0 >= (unsigned)N) s0 = 0;
                unsigned s1 = (unsigned)(r1 >> 40); if (s1 >= (unsigned)N) s1 = 0;
                unsigned s2 = (unsigned)(r2 >> 40); if (s2 >= (unsigned)N) s2 = 0;
                unsigned s3 = (unsigned)(r3 >> 40); if (s3 >= (unsigned)N) s3 = 0;
                uint2 v0 = *(const uint2*)(xh + (size_t)s0 * DIM + (sub << 2));
                uint2 v1 = *(const uint2*)(xh + (size_t)s1 * DIM + (sub << 2));
                uint2 v2 = *(const uint2*)(xh + (size_t)s2 * DIM + (sub << 2));
                uint2 v3 = *(const uint2*)(xh + (size_t)s3 * DIM + (sub << 2));
                float a0 = __uint_as_float((unsigned)r0);
                float a1 = __uint_as_float((unsigned)r1);
                float a2 = __uint_as_float((unsigned)r2);
                float a3 = __uint_as_float((unsigned)r3);
                float2 lo0 = __half22float2(*(const __half2*)&v0.x);
                float2 hi0 = __half22float2(*(const __half2*)&v0.y);
                float2 lo1 = __half22float2(*(const __half2*)&v1.x);
                float2 hi1 = __half22float2(*(const __half2*)&v1.y);
                float2 lo2 = __half22float2(*(const __half2*)&v2.x);
                float2 hi2 = __half22float2(*(const __half2*)&v2.y);
                float2 lo3 = __half22float2(*(const __half2*)&v3.x);
                float2 hi3 = __half22float2(*(const __half2*)&v3.y);
                ax = fmaf(a0, lo0.x, ax); ay = fmaf(a0, lo0.y, ay);
                az = fmaf(a0, hi0.x, az); aw = fmaf(a0, hi0.y, aw);
                ax = fmaf(a1, lo1.x, ax); ay = fmaf(a1, lo1.y, ay);
                az = fmaf(a1, hi1.x, az); aw = fmaf(a1, hi1.y, aw);
                ax = fmaf(a2, lo2.x, ax); ay = fmaf(a2, lo2.y, ay);
                az = fmaf(a2, hi2.x, az); aw = fmaf(a2, hi2.y, aw);
                ax = fmaf(a3, lo3.x, ax); ay = fmaf(a3, lo3.y, ay);
                az = fmaf(a3, hi3.x, az); aw = fmaf(a3, hi3.y, aw);
            }
            if (p < pe) {                         // masked tail quad
                int q1 = p + 1, q2 = p + 2, q3 = p + 3;
                ull r0 = srec[sidx[p]];
                ull r1 = (q1 < pe) ? srec[sidx[q1]] : 0ULL;
                ull r2 = (q2 < pe) ? srec[sidx[q2]] : 0ULL;
                ull r3 = (q3 < pe) ? srec[sidx[q3]] : 0ULL;
                unsigned s0 = (unsigned)(r0 >> 40); if (s0 >= (unsigned)N) s0 = 0;
                unsigned s1 = (unsigned)(r1 >> 40); if (s1 >= (unsigned)N) s1 = 0;
                unsigned s2 = (unsigned)(r2 >> 40); if (s2 >= (unsigned)N) s2 = 0;
                unsigned s3 = (unsigned)(r3 >> 40); if (s3 >= (unsigned)N) s3 = 0;
                uint2 v0 = *(const uint2*)(xh + (size_t)s0 * DIM + (sub << 2));
                uint2 v1 = *(const uint2*)(xh + (size_t)s1 * DIM + (sub << 2));
                uint2 v2 = *(const uint2*)(xh + (size_t)s2 * DIM + (sub << 2));
                uint2 v3 = *(const uint2*)(xh + (size_t)s3 * DIM + (sub << 2));
                float a0 = __uint_as_float((unsigned)r0);
                float a1 = __uint_as_float((unsigned)r1);
                float a2 = __uint_as_float((unsigned)r2);
                float a3 = __uint_as_float((unsigned)r3);
                float2 lo0 = __half22float2(*(const __half2*)&v0.x);
                float2 hi0 = __half22float2(*(const __half2*)&v0.y);
                float2 lo1 = __half22float2(*(const __half2*)&v1.x);
                float2 hi1 = __half22float2(*(const __half2*)&v1.y);
                float2 lo2 = __half22float2(*(const __half2*)&v2.x);
                float2 hi2 = __half22float2(*(const __half2*)&v2.y);
                float2 lo3 = __half22float2(*(const __half2*)&v3.x);
                float2 hi3 = __half22float2(*(const __half2*)&v3.y);
                ax = fmaf(a0, lo0.x, ax); ay = fmaf(a0, lo0.y, ay);
                az = fmaf(a0, hi0.x, az); aw = fmaf(a0, hi0.y, aw);
                ax = fmaf(a1, lo1.x, ax); ay = fmaf(a1, lo1.y, ay);
                az = fmaf(a1, hi1.x, az); aw = fmaf(a1, hi1.y, aw);
                ax = fmaf(a2, lo2.x, ax); ay = fmaf(a2, lo2.y, ay);
                az = fmaf(a2, hi2.x, az); aw = fmaf(a2, hi2.y, aw);
                ax = fmaf(a3, lo3.x, ax); ay = fmaf(a3, lo3.y, ay);
                az = fmaf(a3, hi3.x, az); aw = fmaf(a3, hi3.y, aw);
            }
            if (node < N) {
                *(float4*)(h + (size_t)node * DIM + (sub << 2)) =
                    make_float4(ax, ay, az, aw);
            }
        }
    } else {
        // ---- slow path (cnt > CAP, never for this input): atomic accumulate
        for (int j = tid; j < SPAN * DIM; j += 1024) {
            int node = b * SPAN + (j >> 6);
            if (node < N) h[(size_t)node * DIM + (j & 63)] = 0.f;
        }
        __syncthreads();
        for (int i = tid; i < cnt; i += 1024) {
            ull r = pay[bstart + i];
            unsigned s = (unsigned)(r >> 40);
            if (s >= (unsigned)N) s = 0;
            int node = b * SPAN + (int)((r >> 32) & (SPAN - 1u));
            float a = __uint_as_float((unsigned)r);
            if (node < N)
                for (int k = 0; k < DIM; ++k)
                    atomicAdd(&h[(size_t)node * DIM + k],
                              a * x32[(size_t)s * DIM + k]);
        }
    }
}

// ---------------- Fallback (atomic path, known-good) -----------------------
__global__ void zero_h_kernel(float* __restrict__ p, int n) {
    int i = blockIdx.x * blockDim.x + threadIdx.x;
    if (i < n) p[i] = 0.f;
}

__global__ void edge_kernel_atomic(const float* __restrict__ x,
                                   const float* __restrict__ ew,
                                   const int* __restrict__ src_idx,
                                   const int* __restrict__ dst_idx,
                                   const float* __restrict__ a_src,
                                   const float* __restrict__ a_dst,
                                   float* __restrict__ h,
                                   int E) {
    int gid  = blockIdx.x * blockDim.x + threadIdx.x;
    int e    = gid >> 6;
    int lane = threadIdx.x & 63;
    if (e >= E) return;
    int s = src_idx[e];
    int t = dst_idx[e];
    float a  = tanhf(a_src[s] + a_dst[t]) * ew[e];
    float xv = x[(size_t)s * DIM + lane];
    atomicAdd(&h[(size_t)t * DIM + lane], a * xv);
}

__global__ void score_only_kernel(const float* __restrict__ x,
                                  const float* __restrict__ w_src,
                                  const float* __restrict__ w_dst,
                                  float* __restrict__ a_src,
                                  float* __restrict__ a_dst,
                                  int N) {
    int gid  = blockIdx.x * blockDim.x + threadIdx.x;
    int node = gid >> 6;
    int lane = threadIdx.x & 63;
    if (node >= N) return;
    float xv = x[(size_t)node * DIM + lane];
    float s1 = xv * w_src[lane];
    float s2 = xv * w_dst[lane];
    #pragma unroll
    for (int off = 32; off > 0; off >>= 1) {
        s1 += __shfl_down(s1, off, 64);
        s2 += __shfl_down(s2, off, 64);
    }
    if (lane == 0) {
        a_src[node] = s1;
        a_dst[node] = s2;
    }
}

extern "C" void kernel_launch(void* const* d_in, const int* in_sizes, int n_in,
                              void* d_out, int out_size, void* d_ws, size_t ws_size,
                              hipStream_t stream) {
    const float* x     = (const float*)d_in[0];
    const float* w_src = (const float*)d_in[1];
    const float* w_dst = (const float*)d_in[2];
    const float* ew    = (const float*)d_in[3];
    const int*   src   = (const int*)d_in[4];
    const int*   dst   = (const int*)d_in[5];
    float* h = (float*)d_out;

    int N = in_sizes[0] / DIM;
    int E = in_sizes[3];

    int K = (N + SPAN - 1) / SPAN;        // buckets

    // ws layout (4B units):
    // [a_src N][a_dst N][gcnt K][gbase K+1][gcur K][pad][pay E*8B][xh N*DIM*2B]
    float* a_src = (float*)d_ws;
    float* a_dst = a_src + N;
    int*   gcnt  = (int*)(a_dst + N);
    int*   gbase = gcnt + K;
    int*   gcur  = gbase + K + 1;
    size_t head_bytes = ((size_t)(2 * N) + (size_t)(3 * K + 1)) * 4;
    size_t pay_off = (head_bytes + 15) & ~(size_t)15;
    ull* pay = (ull*)((char*)d_ws + pay_off);
    size_t xh_off = pay_off + (size_t)E * 8;
    __half* xh = (__half*)((char*)d_ws + xh_off);
    size_t need = xh_off + (size_t)N * DIM * 2;

    int score_blocks = (N + 3) / 4;

    if (ws_size < need || K > KMAX || K < 1 || (N * DIM) % 2 != 0) {
        // fallback: known-good atomic path
        score_only_kernel<<<score_blocks, 256, 0, stream>>>(x, w_src, w_dst,
                                                            a_src, a_dst, N);
        int ob = (out_size + 255) / 256;
        zero_h_kernel<<<ob, 256, 0, stream>>>(h, out_size);
        int edge_blocks = (E + 3) / 4;
        edge_kernel_atomic<<<edge_blocks, 256, 0, stream>>>(x, ew, src, dst,
                                                            a_src, a_dst, h, E);
        return;
    }

    score_kernel<<<score_blocks, 256, 0, stream>>>(x, w_src, w_dst,
                                                   a_src, a_dst, xh,
                                                   gcnt, N, K);
    hist_kernel<<<256, 1024, 0, stream>>>(dst, gcnt, E, N, K);
    scan_kernel<<<1, 512, 0, stream>>>(gcnt, gbase, gcur, K, E);
    int bp_blocks = ((E + 1) / 2 + 255) / 256;
    binpass_atomic<<<bp_blocks, 256, 0, stream>>>(ew, src, dst, a_src, a_dst,
                                                  gcur, pay, E, N);
    sort_gather_kernel<<<K, 1024, 0, stream>>>(xh, x, pay, gbase,
                                               h, N, K, E);
}

// Round 12
// 174.248 us; speedup vs baseline: 3.4577x; 3.4577x over previous
//
#include <hip/hip_runtime.h>
#include <hip/hip_fp16.h>
#include <math.h>

#define DIM  64
#define SPAN 256            // nodes per bucket (dst>>8)
#define SPAN_SHIFT 8
#define NBIN 256            // binning blocks (private (block,bucket) segments)
#define KMAX 512            // max buckets (N <= 131072)
#define CAP  6144           // LDS staging capacity per bucket (48 KB)

// ---------------- Kernel 1: per-node scores + fp16 x copy ------------------
__global__ void score_kernel(const float* __restrict__ x,
                             const float* __restrict__ w_src,
                             const float* __restrict__ w_dst,
                             float* __restrict__ a_src,
                             float* __restrict__ a_dst,
                             __half* __restrict__ xh,
                             int N) {
    int gid  = blockIdx.x * blockDim.x + threadIdx.x;
    int node = gid >> 6;
    int lane = threadIdx.x & 63;
    if (node >= N) return;
    float xv = x[(size_t)node * DIM + lane];
    xh[(size_t)node * DIM + lane] = __float2half_rn(xv);
    float s1 = xv * w_src[lane];
    float s2 = xv * w_dst[lane];
    #pragma unroll
    for (int off = 32; off > 0; off >>= 1) {
        s1 += __shfl_down(s1, off, 64);
        s2 += __shfl_down(s2, off, 64);
    }
    if (lane == 0) {
        a_src[node] = s1;
        a_dst[node] = s2;
    }
}

// ---------------- Kernel 2: coarse histogram matrix ------------------------
// cnt[bucket * NBIN + block] = #edges of bucket seen by block. Deterministic
// membership. 2 edges/thread, int2 loads; partition MUST match binpass.
__global__ __launch_bounds__(1024) void hist_coarse(
        const int* __restrict__ dst, int* __restrict__ cnt,
        int E, int N, int K) {
    __shared__ int lh[KMAX];
    int tid = threadIdx.x;
    for (int j = tid; j < K; j += blockDim.x) lh[j] = 0;
    __syncthreads();
    for (int base = blockIdx.x * 2048; base < E; base += NBIN * 2048) {
        int e = base + (tid << 1);
        if (e + 1 < E) {
            int2 t2 = *(const int2*)(dst + e);
            unsigned t0 = (unsigned)t2.x; if (t0 >= (unsigned)N) t0 = 0;
            unsigned t1 = (unsigned)t2.y; if (t1 >= (unsigned)N) t1 = 0;
            atomicAdd(&lh[t0 >> SPAN_SHIFT], 1);
            atomicAdd(&lh[t1 >> SPAN_SHIFT], 1);
        } else if (e < E) {
            unsigned t = (unsigned)dst[e];
            if (t >= (unsigned)N) t = 0;          // guard
            atomicAdd(&lh[t >> SPAN_SHIFT], 1);
        }
    }
    __syncthreads();
    for (int j = tid; j < K; j += blockDim.x)
        cnt[j * NBIN + blockIdx.x] = lh[j];
}

// ---------------- Kernels 3-4: exclusive scan (double-buffered HS) ---------
__global__ void scan_part(const int* __restrict__ cnt, int* __restrict__ offs,
                          int* __restrict__ bsum, int N) {
    __shared__ int buf[2][256];
    int tid = threadIdx.x;
    int i = blockIdx.x * 256 + tid;
    int v = (i < N) ? cnt[i] : 0;
    int sel = 0;
    buf[0][tid] = v;
    __syncthreads();
    for (int off = 1; off < 256; off <<= 1) {
        int nsel = sel ^ 1;
        buf[nsel][tid] = buf[sel][tid] + ((tid >= off) ? buf[sel][tid - off] : 0);
        __syncthreads();
        sel = nsel;
    }
    if (i < N) offs[i] = buf[sel][tid] - v;
    if (tid == 255) bsum[blockIdx.x] = buf[sel][255];
}

__global__ void scan_top(int* __restrict__ bsum, int* __restrict__ offs,
                         int NB, int N) {
    __shared__ int buf[2][512];
    int tid = threadIdx.x;
    int v = (tid < NB) ? bsum[tid] : 0;
    int sel = 0;
    buf[0][tid] = v;
    __syncthreads();
    for (int off = 1; off < 512; off <<= 1) {
        int nsel = sel ^ 1;
        buf[nsel][tid] = buf[sel][tid] + ((tid >= off) ? buf[sel][tid - off] : 0);
        __syncthreads();
        sel = nsel;
    }
    if (tid < NB) bsum[tid] = buf[sel][tid] - v;
    if (tid == 511) offs[N] = buf[sel][511];      // grand total (unused)
}

// ---------------- Kernel 5: binpass — bucket-grouped payload ---------------
// LDS cursors over private (block,bucket) segments => no global contention.
// 2 edges/thread, int2/float2 loads; partition matches hist_coarse.
__global__ __launch_bounds__(1024) void binpass_kernel(
        const float* __restrict__ ew,
        const int* __restrict__ src_idx,
        const int* __restrict__ dst_idx,
        const float* __restrict__ a_src,
        const float* __restrict__ a_dst,
        const int* __restrict__ moffs,
        const int* __restrict__ bsum,
        unsigned long long* __restrict__ pay,
        int E, int N, int K) {
    __shared__ int lcur[KMAX];
    int tid = threadIdx.x;
    for (int j = tid; j < K; j += blockDim.x) {
        int i = j * NBIN + blockIdx.x;
        lcur[j] = moffs[i] + bsum[i >> 8];
    }
    __syncthreads();
    for (int base = blockIdx.x * 2048; base < E; base += NBIN * 2048) {
        int e = base + (tid << 1);
        if (e + 1 < E) {
            int2   s2 = *(const int2*)(src_idx + e);
            int2   t2 = *(const int2*)(dst_idx + e);
            float2 w2 = *(const float2*)(ew + e);
            unsigned s0 = (unsigned)s2.x; if (s0 >= (unsigned)N) s0 = 0;
            unsigned t0 = (unsigned)t2.x; if (t0 >= (unsigned)N) t0 = 0;
            unsigned s1 = (unsigned)s2.y; if (s1 >= (unsigned)N) s1 = 0;
            unsigned t1 = (unsigned)t2.y; if (t1 >= (unsigned)N) t1 = 0;
            float a0 = tanhf(a_src[s0] + a_dst[t0]) * w2.x;
            float a1 = tanhf(a_src[s1] + a_dst[t1]) * w2.y;
            int p0 = atomicAdd(&lcur[t0 >> SPAN_SHIFT], 1);
            int p1 = atomicAdd(&lcur[t1 >> SPAN_SHIFT], 1);
            unsigned r0 = (s0 << 8) | (t0 & (SPAN - 1u));
            unsigned r1 = (s1 << 8) | (t1 & (SPAN - 1u));
            pay[p0] = ((unsigned long long)r0 << 32) |
                      (unsigned long long)__float_as_uint(a0);
            pay[p1] = ((unsigned long long)r1 << 32) |
                      (unsigned long long)__float_as_uint(a1);
        } else if (e < E) {
            unsigned s = (unsigned)src_idx[e];
            unsigned t = (unsigned)dst_idx[e];
            if (s >= (unsigned)N) s = 0;          // guard
            if (t >= (unsigned)N) t = 0;          // guard
            float a = tanhf(a_src[s] + a_dst[t]) * ew[e];
            int pos = atomicAdd(&lcur[t >> SPAN_SHIFT], 1);
            unsigned rec = (s << 8) | (t & (SPAN - 1u));
            pay[pos] = ((unsigned long long)rec << 32) |
                       (unsigned long long)__float_as_uint(a);
        }
    }
}

// ---------------- Kernel 6: fused per-bucket sort + gather -----------------
// Round-5 verified version (45.1 us): 4 edges per wave-load, butterfly
// reduce across 4 edge-groups, lanes 0..15 store one float4.
__global__ __launch_bounds__(1024) void sort_gather_kernel(
        const __half* __restrict__ xh,
        const float* __restrict__ x32,
        const unsigned long long* __restrict__ pay,
        const int* __restrict__ moffs,
        const int* __restrict__ bsum,
        float* __restrict__ h,
        int N, int K, int E) {
    __shared__ unsigned long long srec[CAP];      // 48 KB
    __shared__ unsigned short sidx[CAP];          // 12 KB
    __shared__ int hcnt[SPAN];
    __shared__ int hoff[2][SPAN];
    __shared__ int lcur[SPAN];
    __shared__ int nstart[SPAN];
    int tid = threadIdx.x;
    int b   = blockIdx.x;
    int i0 = b * NBIN;
    int bstart = moffs[i0] + bsum[i0 >> 8];
    int bend;
    if (b == K - 1) bend = E;
    else { int i1 = (b + 1) * NBIN; bend = moffs[i1] + bsum[i1 >> 8]; }
    int cnt = bend - bstart;

    if (cnt <= CAP) {
        // ---- stage + histogram ----
        if (tid < SPAN) hcnt[tid] = 0;
        __syncthreads();
        for (int i = tid; i < cnt; i += 1024) {
            unsigned long long r = pay[bstart + i];
            srec[i] = r;
            atomicAdd(&hcnt[(int)((r >> 32) & (SPAN - 1u))], 1);
        }
        __syncthreads();
        // ---- inclusive scan of hcnt[SPAN] ----
        int sel = 0;
        if (tid < SPAN) hoff[0][tid] = hcnt[tid];
        __syncthreads();
        for (int off = 1; off < SPAN; off <<= 1) {
            int nsel = sel ^ 1;
            if (tid < SPAN)
                hoff[nsel][tid] = hoff[sel][tid] +
                                  ((tid >= off) ? hoff[sel][tid - off] : 0);
            __syncthreads();
            sel = nsel;
        }
        if (tid < SPAN) {
            int excl = hoff[sel][tid] - hcnt[tid];
            nstart[tid] = excl;
            lcur[tid]   = excl;
        }
        __syncthreads();
        // ---- permute indices only (sidx), srec stays put ----
        for (int i = tid; i < cnt; i += 1024) {
            unsigned long long r = srec[i];
            int d = (int)((r >> 32) & (SPAN - 1u));
            int pos = atomicAdd(&lcur[d], 1);
            sidx[pos] = (unsigned short)i;
        }
        __syncthreads();
        // ---- gather phase: wave per node, 4 edges per load instruction ----
        int lane = tid & 63;
        int wave = tid >> 6;                      // 16 waves
        int grp  = lane >> 4;                     // edge slot 0..3
        int sub  = lane & 15;                     // dim quad
        for (int d = wave; d < SPAN; d += 16) {
            int node = b * SPAN + d;
            if (node >= N) break;                 // only last bucket; d monotone
            int p  = nstart[d];
            int pe = p + hcnt[d];
            float ax = 0.f, ay = 0.f, az = 0.f, aw = 0.f;
            while (p + 8 <= pe) {
                unsigned long long r0 = srec[sidx[p + grp]];
                unsigned long long r1 = srec[sidx[p + 4 + grp]];
                p += 8;
                unsigned s0 = (unsigned)(r0 >> 40); if (s0 >= (unsigned)N) s0 = 0;
                unsigned s1 = (unsigned)(r1 >> 40); if (s1 >= (unsigned)N) s1 = 0;
                uint2 v0 = *(const uint2*)(xh + (size_t)s0 * DIM + (sub << 2));
                uint2 v1 = *(const uint2*)(xh + (size_t)s1 * DIM + (sub << 2));
                float a0 = __uint_as_float((unsigned)r0);
                float a1 = __uint_as_float((unsigned)r1);
                float2 l0 = __half22float2(*(const __half2*)&v0.x);
                float2 h0 = __half22float2(*(const __half2*)&v0.y);
                float2 l1 = __half22float2(*(const __half2*)&v1.x);
                float2 h1 = __half22float2(*(const __half2*)&v1.y);
                ax = fmaf(a0, l0.x, ax); ay = fmaf(a0, l0.y, ay);
                az = fmaf(a0, h0.x, az); aw = fmaf(a0, h0.y, aw);
                ax = fmaf(a1, l1.x, ax); ay = fmaf(a1, l1.y, ay);
                az = fmaf(a1, h1.x, az); aw = fmaf(a1, h1.y, aw);
            }
            while (p < pe) {
                int q = p + grp;
                float a0 = 0.f;
                unsigned s0 = 0;
                if (q < pe) {
                    unsigned long long r0 = srec[sidx[q]];
                    a0 = __uint_as_float((unsigned)r0);
                    s0 = (unsigned)(r0 >> 40); if (s0 >= (unsigned)N) s0 = 0;
                }
                p += 4;
                uint2 v0 = *(const uint2*)(xh + (size_t)s0 * DIM + (sub << 2));
                float2 l0 = __half22float2(*(const __half2*)&v0.x);
                float2 h0 = __half22float2(*(const __half2*)&v0.y);
                ax = fmaf(a0, l0.x, ax); ay = fmaf(a0, l0.y, ay);
                az = fmaf(a0, h0.x, az); aw = fmaf(a0, h0.y, aw);
            }
            // butterfly reduce across the 4 edge-groups (lanes ^16, ^32)
            ax += __shfl_xor(ax, 16, 64); ay += __shfl_xor(ay, 16, 64);
            az += __shfl_xor(az, 16, 64); aw += __shfl_xor(aw, 16, 64);
            ax += __shfl_xor(ax, 32, 64); ay += __shfl_xor(ay, 32, 64);
            az += __shfl_xor(az, 32, 64); aw += __shfl_xor(aw, 32, 64);
            if (grp == 0) {
                float4 out = make_float4(ax, ay, az, aw);
                *(float4*)(h + (size_t)node * DIM + (sub << 2)) = out;
            }
        }
    } else {
        // ---- slow path (cnt > CAP, never for this input): atomic accumulate
        for (int j = tid; j < SPAN * DIM; j += 1024) {
            int node = b * SPAN + (j >> 6);
            if (node < N) h[(size_t)node * DIM + (j & 63)] = 0.f;
        }
        __syncthreads();
        for (int i = tid; i < cnt; i += 1024) {
            unsigned long long r = pay[bstart + i];
            unsigned s = (unsigned)(r >> 40);
            if (s >= (unsigned)N) s = 0;
            int node = b * SPAN + (int)((r >> 32) & (SPAN - 1u));
            float a = __uint_as_float((unsigned)r);
            if (node < N)
                for (int k = 0; k < DIM; ++k)
                    atomicAdd(&h[(size_t)node * DIM + k],
                              a * x32[(size_t)s * DIM + k]);
        }
    }
}

// ---------------- Fallback (atomic path, known-good) -----------------------
__global__ void zero_h_kernel(float* __restrict__ p, int n) {
    int i = blockIdx.x * blockDim.x + threadIdx.x;
    if (i < n) p[i] = 0.f;
}

__global__ void edge_kernel_atomic(const float* __restrict__ x,
                                   const float* __restrict__ ew,
                                   const int* __restrict__ src_idx,
                                   const int* __restrict__ dst_idx,
                                   const float* __restrict__ a_src,
                                   const float* __restrict__ a_dst,
                                   float* __restrict__ h,
                                   int E) {
    int gid  = blockIdx.x * blockDim.x + threadIdx.x;
    int e    = gid >> 6;
    int lane = threadIdx.x & 63;
    if (e >= E) return;
    int s = src_idx[e];
    int t = dst_idx[e];
    float a  = tanhf(a_src[s] + a_dst[t]) * ew[e];
    float xv = x[(size_t)s * DIM + lane];
    atomicAdd(&h[(size_t)t * DIM + lane], a * xv);
}

__global__ void score_only_kernel(const float* __restrict__ x,
                                  const float* __restrict__ w_src,
                                  const float* __restrict__ w_dst,
                                  float* __restrict__ a_src,
                                  float* __restrict__ a_dst,
                                  int N) {
    int gid  = blockIdx.x * blockDim.x + threadIdx.x;
    int node = gid >> 6;
    int lane = threadIdx.x & 63;
    if (node >= N) return;
    float xv = x[(size_t)node * DIM + lane];
    float s1 = xv * w_src[lane];
    float s2 = xv * w_dst[lane];
    #pragma unroll
    for (int off = 32; off > 0; off >>= 1) {
        s1 += __shfl_down(s1, off, 64);
        s2 += __shfl_down(s2, off, 64);
    }
    if (lane == 0) {
        a_src[node] = s1;
        a_dst[node] = s2;
    }
}

extern "C" void kernel_launch(void* const* d_in, const int* in_sizes, int n_in,
                              void* d_out, int out_size, void* d_ws, size_t ws_size,
                              hipStream_t stream) {
    const float* x     = (const float*)d_in[0];
    const float* w_src = (const float*)d_in[1];
    const float* w_dst = (const float*)d_in[2];
    const float* ew    = (const float*)d_in[3];
    const int*   src   = (const int*)d_in[4];
    const int*   dst   = (const int*)d_in[5];
    float* h = (float*)d_out;

    int N = in_sizes[0] / DIM;
    int E = in_sizes[3];

    int K    = (N + SPAN - 1) / SPAN;     // buckets
    int Ntot = K * NBIN;                  // count-matrix entries
    int NBs  = (Ntot + 255) / 256;        // scan blocks

    // ws layout (4B units):
    // [a_src N][a_dst N][moffs Ntot+1][bsum NBs][pad][pay E*8B][xh N*DIM*2B]
    float* a_src  = (float*)d_ws;
    float* a_dst  = a_src + N;
    int*   moffs  = (int*)(a_dst + N);
    int*   bsum   = moffs + Ntot + 1;
    size_t head_bytes = ((size_t)(2 * N) + (size_t)Ntot + 1 + (size_t)NBs) * 4;
    size_t pay_off = (head_bytes + 15) & ~(size_t)15;
    unsigned long long* pay = (unsigned long long*)((char*)d_ws + pay_off);
    size_t xh_off = pay_off + (size_t)E * 8;
    __half* xh = (__half*)((char*)d_ws + xh_off);
    size_t need = xh_off + (size_t)N * DIM * 2;

    int score_blocks = (N + 3) / 4;

    if (ws_size < need || K > KMAX || NBs > 512 || (N * DIM) % 2 != 0) {
        // fallback: known-good atomic path
        score_only_kernel<<<score_blocks, 256, 0, stream>>>(x, w_src, w_dst,
                                                            a_src, a_dst, N);
        int ob = (out_size + 255) / 256;
        zero_h_kernel<<<ob, 256, 0, stream>>>(h, out_size);
        int edge_blocks = (E + 3) / 4;
        edge_kernel_atomic<<<edge_blocks, 256, 0, stream>>>(x, ew, src, dst,
                                                            a_src, a_dst, h, E);
        return;
    }

    score_kernel<<<score_blocks, 256, 0, stream>>>(x, w_src, w_dst,
                                                   a_src, a_dst, xh, N);
    hist_coarse<<<NBIN, 1024, 0, stream>>>(dst, moffs, E, N, K);
    scan_part<<<NBs, 256, 0, stream>>>(moffs, moffs, bsum, Ntot);
    scan_top<<<1, 512, 0, stream>>>(bsum, moffs, NBs, Ntot);
    binpass_kernel<<<NBIN, 1024, 0, stream>>>(ew, src, dst, a_src, a_dst,
                                              moffs, bsum, pay, E, N, K);
    sort_gather_kernel<<<K, 1024, 0, stream>>>(xh, x, pay, moffs, bsum,
                                               h, N, K, E);
}

// Round 13
// 161.974 us; speedup vs baseline: 3.7197x; 1.0758x over previous
//
#include <hip/hip_runtime.h>
#include <hip/hip_fp16.h>
#include <math.h>

typedef unsigned long long ull;

#define DIM  64
#define SPAN 256            // nodes per bucket (dst>>8)
#define SPAN_SHIFT 8
#define NBIN 256            // binning blocks (private (block,bucket) segments)
#define KMAX 512            // max buckets (N <= 131072)
#define CAP  6144           // LDS staging capacity per bucket (48 KB)

// ---------------- Kernel 1: fused score (+xh) | coarse histogram -----------
// 256 threads: 4 waves x 4 nodes/wave (float4 loads, 16 lanes/node).
// Blocks 0..NBIN-1 additionally run the hist loop; per-block edge SET
// matches binpass's partition (chunks [b*2048 + k*NBIN*2048, +2048)).
__global__ __launch_bounds__(256) void score_hist_kernel(
        const float* __restrict__ x,
        const float* __restrict__ w_src,
        const float* __restrict__ w_dst,
        const int* __restrict__ dst_idx,
        float* __restrict__ a_src,
        float* __restrict__ a_dst,
        __half* __restrict__ xh,
        int* __restrict__ cnt,            // [K*NBIN] histogram matrix
        int N, int E, int K) {
    __shared__ int lh[KMAX];
    int tid = threadIdx.x;
    int b   = blockIdx.x;
    bool histblk = (b < NBIN);
    if (histblk) {
        for (int j = tid; j < K; j += 256) lh[j] = 0;
        __syncthreads();
    }
    // ---- score part: 16 nodes/block ----
    int lane = tid & 63;
    int wave = tid >> 6;                  // 0..3
    int grp  = lane >> 4;                 // node slot 0..3
    int sub  = lane & 15;                 // dim quad
    int node = b * 16 + wave * 4 + grp;
    if (node < N) {
        float4 v  = ((const float4*)x)[(size_t)node * 16 + sub];
        float4 ws = ((const float4*)w_src)[sub];
        float4 wd = ((const float4*)w_dst)[sub];
        float s1 = v.x * ws.x + v.y * ws.y + v.z * ws.z + v.w * ws.w;
        float s2 = v.x * wd.x + v.y * wd.y + v.z * wd.z + v.w * wd.w;
        #pragma unroll
        for (int off = 1; off < 16; off <<= 1) {
            s1 += __shfl_xor(s1, off, 64);
            s2 += __shfl_xor(s2, off, 64);
        }
        if (sub == 0) { a_src[node] = s1; a_dst[node] = s2; }
        __half2 h01 = __floats2half2_rn(v.x, v.y);
        __half2 h23 = __floats2half2_rn(v.z, v.w);
        uint2 hv;
        hv.x = *(unsigned*)&h01;
        hv.y = *(unsigned*)&h23;
        *(uint2*)(xh + (size_t)node * DIM + (sub << 2)) = hv;
    }
    // ---- hist part (blocks 0..NBIN-1) ----
    if (histblk) {
        for (int base = b * 2048; base < E; base += NBIN * 2048) {
            for (int off = tid << 1; off < 2048; off += 512) {
                int e = base + off;
                if (e + 1 < E) {
                    int2 t2 = *(const int2*)(dst_idx + e);
                    unsigned t0 = (unsigned)t2.x; if (t0 >= (unsigned)N) t0 = 0;
                    unsigned t1 = (unsigned)t2.y; if (t1 >= (unsigned)N) t1 = 0;
                    atomicAdd(&lh[t0 >> SPAN_SHIFT], 1);
                    atomicAdd(&lh[t1 >> SPAN_SHIFT], 1);
                } else if (e < E) {
                    unsigned t = (unsigned)dst_idx[e];
                    if (t >= (unsigned)N) t = 0;          // guard
                    atomicAdd(&lh[t >> SPAN_SHIFT], 1);
                }
            }
        }
        __syncthreads();
        for (int j = tid; j < K; j += 256) cnt[j * NBIN + b] = lh[j];
    }
}

// ---------------- Kernel 2: per-chunk exclusive scan (in-place safe) -------
__global__ void scan_part(const int* __restrict__ cnt, int* __restrict__ offs,
                          int* __restrict__ bsum, int N) {
    __shared__ int buf[2][256];
    int tid = threadIdx.x;
    int i = blockIdx.x * 256 + tid;
    int v = (i < N) ? cnt[i] : 0;
    int sel = 0;
    buf[0][tid] = v;
    __syncthreads();
    for (int off = 1; off < 256; off <<= 1) {
        int nsel = sel ^ 1;
        buf[nsel][tid] = buf[sel][tid] + ((tid >= off) ? buf[sel][tid - off] : 0);
        __syncthreads();
        sel = nsel;
    }
    if (i < N) offs[i] = buf[sel][tid] - v;
    if (tid == 255) bsum[blockIdx.x] = buf[sel][255];
}

// ---------------- Kernel 3: binpass — LDS top-scan + bucket payload --------
// Each block re-derives the exclusive top-scan of bsum[NBs<=512] in LDS
// (NBIN==chunk==256 => bsum[c] is bucket c's total; topscan[c] = bucket
// start). Block 0 publishes gbase[0..K] for sort_gather. Edge loop:
// 2 edges/thread, int2/float2 loads; partition matches score_hist.
__global__ __launch_bounds__(1024) void binpass_kernel(
        const float* __restrict__ ew,
        const int* __restrict__ src_idx,
        const int* __restrict__ dst_idx,
        const float* __restrict__ a_src,
        const float* __restrict__ a_dst,
        const int* __restrict__ moffs,
        const int* __restrict__ bsum,
        int* __restrict__ gbase,
        ull* __restrict__ pay,
        int E, int N, int K, int NBs) {
    __shared__ int lcur[KMAX];
    __shared__ int buf[2][512];
    int tid = threadIdx.x;
    int b   = blockIdx.x;
    // ---- exclusive top-scan of bsum in LDS ----
    int v = 0;
    if (tid < 512) {
        v = (tid < NBs) ? bsum[tid] : 0;
        buf[0][tid] = v;
    }
    __syncthreads();
    int sel = 0;
    for (int off = 1; off < 512; off <<= 1) {
        if (tid < 512)
            buf[sel ^ 1][tid] = buf[sel][tid] +
                                ((tid >= off) ? buf[sel][tid - off] : 0);
        __syncthreads();
        sel ^= 1;
    }
    int esel = sel ^ 1;                   // free buffer for exclusive values
    if (tid < 512) buf[esel][tid] = buf[sel][tid] - v;
    __syncthreads();
    if (b == 0 && tid < 512) {
        if (tid < NBs) gbase[tid] = buf[esel][tid];
        if (tid == NBs) gbase[NBs] = E;   // NBs == K
    }
    // ---- init private cursors: moffs chunk-scan + bucket base ----
    for (int j = tid; j < K; j += 1024)
        lcur[j] = moffs[j * NBIN + b] + buf[esel][j];
    __syncthreads();
    // ---- edge loop ----
    for (int base = b * 2048; base < E; base += NBIN * 2048) {
        int e = base + (tid << 1);
        if (e + 1 < E) {
            int2   s2 = *(const int2*)(src_idx + e);
            int2   t2 = *(const int2*)(dst_idx + e);
            float2 w2 = *(const float2*)(ew + e);
            unsigned s0 = (unsigned)s2.x; if (s0 >= (unsigned)N) s0 = 0;
            unsigned t0 = (unsigned)t2.x; if (t0 >= (unsigned)N) t0 = 0;
            unsigned s1 = (unsigned)s2.y; if (s1 >= (unsigned)N) s1 = 0;
            unsigned t1 = (unsigned)t2.y; if (t1 >= (unsigned)N) t1 = 0;
            float a0 = tanhf(a_src[s0] + a_dst[t0]) * w2.x;
            float a1 = tanhf(a_src[s1] + a_dst[t1]) * w2.y;
            int p0 = atomicAdd(&lcur[t0 >> SPAN_SHIFT], 1);
            int p1 = atomicAdd(&lcur[t1 >> SPAN_SHIFT], 1);
            unsigned r0 = (s0 << 8) | (t0 & (SPAN - 1u));
            unsigned r1 = (s1 << 8) | (t1 & (SPAN - 1u));
            pay[p0] = ((ull)r0 << 32) | (ull)__float_as_uint(a0);
            pay[p1] = ((ull)r1 << 32) | (ull)__float_as_uint(a1);
        } else if (e < E) {
            unsigned s = (unsigned)src_idx[e];
            unsigned t = (unsigned)dst_idx[e];
            if (s >= (unsigned)N) s = 0;          // guard
            if (t >= (unsigned)N) t = 0;          // guard
            float a = tanhf(a_src[s] + a_dst[t]) * ew[e];
            int pos = atomicAdd(&lcur[t >> SPAN_SHIFT], 1);
            unsigned rec = (s << 8) | (t & (SPAN - 1u));
            pay[pos] = ((ull)rec << 32) | (ull)__float_as_uint(a);
        }
    }
}

// ---------------- Kernel 4: fused per-bucket sort + gather -----------------
// Round-5/12 verified core (44.6 us); bucket bounds now from gbase.
__global__ __launch_bounds__(1024) void sort_gather_kernel(
        const __half* __restrict__ xh,
        const float* __restrict__ x32,
        const ull* __restrict__ pay,
        const int* __restrict__ gbase,
        float* __restrict__ h,
        int N, int K, int E) {
    __shared__ ull srec[CAP];                     // 48 KB
    __shared__ unsigned short sidx[CAP];          // 12 KB
    __shared__ int hcnt[SPAN];
    __shared__ int hoff[2][SPAN];
    __shared__ int lcur[SPAN];
    __shared__ int nstart[SPAN];
    int tid = threadIdx.x;
    int b   = blockIdx.x;
    int bstart = gbase[b];
    int bend   = gbase[b + 1];
    int cnt = bend - bstart;

    if (cnt <= CAP) {
        // ---- stage + histogram ----
        if (tid < SPAN) hcnt[tid] = 0;
        __syncthreads();
        for (int i = tid; i < cnt; i += 1024) {
            ull r = pay[bstart + i];
            srec[i] = r;
            atomicAdd(&hcnt[(int)((r >> 32) & (SPAN - 1u))], 1);
        }
        __syncthreads();
        // ---- inclusive scan of hcnt[SPAN] ----
        int sel = 0;
        if (tid < SPAN) hoff[0][tid] = hcnt[tid];
        __syncthreads();
        for (int off = 1; off < SPAN; off <<= 1) {
            int nsel = sel ^ 1;
            if (tid < SPAN)
                hoff[nsel][tid] = hoff[sel][tid] +
                                  ((tid >= off) ? hoff[sel][tid - off] : 0);
            __syncthreads();
            sel = nsel;
        }
        if (tid < SPAN) {
            int excl = hoff[sel][tid] - hcnt[tid];
            nstart[tid] = excl;
            lcur[tid]   = excl;
        }
        __syncthreads();
        // ---- permute indices only (sidx), srec stays put ----
        for (int i = tid; i < cnt; i += 1024) {
            ull r = srec[i];
            int d = (int)((r >> 32) & (SPAN - 1u));
            int pos = atomicAdd(&lcur[d], 1);
            sidx[pos] = (unsigned short)i;
        }
        __syncthreads();
        // ---- gather phase: wave per node, 4 edges per load instruction ----
        int lane = tid & 63;
        int wave = tid >> 6;                      // 16 waves
        int grp  = lane >> 4;                     // edge slot 0..3
        int sub  = lane & 15;                     // dim quad
        for (int d = wave; d < SPAN; d += 16) {
            int node = b * SPAN + d;
            if (node >= N) break;                 // only last bucket; d monotone
            int p  = nstart[d];
            int pe = p + hcnt[d];
            float ax = 0.f, ay = 0.f, az = 0.f, aw = 0.f;
            while (p + 8 <= pe) {
                ull r0 = srec[sidx[p + grp]];
                ull r1 = srec[sidx[p + 4 + grp]];
                p += 8;
                unsigned s0 = (unsigned)(r0 >> 40); if (s0 >= (unsigned)N) s0 = 0;
                unsigned s1 = (unsigned)(r1 >> 40); if (s1 >= (unsigned)N) s1 = 0;
                uint2 v0 = *(const uint2*)(xh + (size_t)s0 * DIM + (sub << 2));
                uint2 v1 = *(const uint2*)(xh + (size_t)s1 * DIM + (sub << 2));
                float a0 = __uint_as_float((unsigned)r0);
                float a1 = __uint_as_float((unsigned)r1);
                float2 l0 = __half22float2(*(const __half2*)&v0.x);
                float2 h0 = __half22float2(*(const __half2*)&v0.y);
                float2 l1 = __half22float2(*(const __half2*)&v1.x);
                float2 h1 = __half22float2(*(const __half2*)&v1.y);
                ax = fmaf(a0, l0.x, ax); ay = fmaf(a0, l0.y, ay);
                az = fmaf(a0, h0.x, az); aw = fmaf(a0, h0.y, aw);
                ax = fmaf(a1, l1.x, ax); ay = fmaf(a1, l1.y, ay);
                az = fmaf(a1, h1.x, az); aw = fmaf(a1, h1.y, aw);
            }
            while (p < pe) {
                int q = p + grp;
                float a0 = 0.f;
                unsigned s0 = 0;
                if (q < pe) {
                    ull r0 = srec[sidx[q]];
                    a0 = __uint_as_float((unsigned)r0);
                    s0 = (unsigned)(r0 >> 40); if (s0 >= (unsigned)N) s0 = 0;
                }
                p += 4;
                uint2 v0 = *(const uint2*)(xh + (size_t)s0 * DIM + (sub << 2));
                float2 l0 = __half22float2(*(const __half2*)&v0.x);
                float2 h0 = __half22float2(*(const __half2*)&v0.y);
                ax = fmaf(a0, l0.x, ax); ay = fmaf(a0, l0.y, ay);
                az = fmaf(a0, h0.x, az); aw = fmaf(a0, h0.y, aw);
            }
            // butterfly reduce across the 4 edge-groups (lanes ^16, ^32)
            ax += __shfl_xor(ax, 16, 64); ay += __shfl_xor(ay, 16, 64);
            az += __shfl_xor(az, 16, 64); aw += __shfl_xor(aw, 16, 64);
            ax += __shfl_xor(ax, 32, 64); ay += __shfl_xor(ay, 32, 64);
            az += __shfl_xor(az, 32, 64); aw += __shfl_xor(aw, 32, 64);
            if (grp == 0) {
                float4 out = make_float4(ax, ay, az, aw);
                *(float4*)(h + (size_t)node * DIM + (sub << 2)) = out;
            }
        }
    } else {
        // ---- slow path (cnt > CAP, never for this input): atomic accumulate
        for (int j = tid; j < SPAN * DIM; j += 1024) {
            int node = b * SPAN + (j >> 6);
            if (node < N) h[(size_t)node * DIM + (j & 63)] = 0.f;
        }
        __syncthreads();
        for (int i = tid; i < cnt; i += 1024) {
            ull r = pay[bstart + i];
            unsigned s = (unsigned)(r >> 40);
            if (s >= (unsigned)N) s = 0;
            int node = b * SPAN + (int)((r >> 32) & (SPAN - 1u));
            float a = __uint_as_float((unsigned)r);
            if (node < N)
                for (int k = 0; k < DIM; ++k)
                    atomicAdd(&h[(size_t)node * DIM + k],
                              a * x32[(size_t)s * DIM + k]);
        }
    }
}

// ---------------- Fallback (atomic path, known-good) -----------------------
__global__ void zero_h_kernel(float* __restrict__ p, int n) {
    int i = blockIdx.x * blockDim.x + threadIdx.x;
    if (i < n) p[i] = 0.f;
}

__global__ void edge_kernel_atomic(const float* __restrict__ x,
                                   const float* __restrict__ ew,
                                   const int* __restrict__ src_idx,
                                   const int* __restrict__ dst_idx,
                                   const float* __restrict__ a_src,
                                   const float* __restrict__ a_dst,
                                   float* __restrict__ h,
                                   int E) {
    int gid  = blockIdx.x * blockDim.x + threadIdx.x;
    int e    = gid >> 6;
    int lane = threadIdx.x & 63;
    if (e >= E) return;
    int s = src_idx[e];
    int t = dst_idx[e];
    float a  = tanhf(a_src[s] + a_dst[t]) * ew[e];
    float xv = x[(size_t)s * DIM + lane];
    atomicAdd(&h[(size_t)t * DIM + lane], a * xv);
}

__global__ void score_only_kernel(const float* __restrict__ x,
                                  const float* __restrict__ w_src,
                                  const float* __restrict__ w_dst,
                                  float* __restrict__ a_src,
                                  float* __restrict__ a_dst,
                                  int N) {
    int gid  = blockIdx.x * blockDim.x + threadIdx.x;
    int node = gid >> 6;
    int lane = threadIdx.x & 63;
    if (node >= N) return;
    float xv = x[(size_t)node * DIM + lane];
    float s1 = xv * w_src[lane];
    float s2 = xv * w_dst[lane];
    #pragma unroll
    for (int off = 32; off > 0; off >>= 1) {
        s1 += __shfl_down(s1, off, 64);
        s2 += __shfl_down(s2, off, 64);
    }
    if (lane == 0) {
        a_src[node] = s1;
        a_dst[node] = s2;
    }
}

extern "C" void kernel_launch(void* const* d_in, const int* in_sizes, int n_in,
                              void* d_out, int out_size, void* d_ws, size_t ws_size,
                              hipStream_t stream) {
    const float* x     = (const float*)d_in[0];
    const float* w_src = (const float*)d_in[1];
    const float* w_dst = (const float*)d_in[2];
    const float* ew    = (const float*)d_in[3];
    const int*   src   = (const int*)d_in[4];
    const int*   dst   = (const int*)d_in[5];
    float* h = (float*)d_out;

    int N = in_sizes[0] / DIM;
    int E = in_sizes[3];

    int K    = (N + SPAN - 1) / SPAN;     // buckets
    int Ntot = K * NBIN;                  // count-matrix entries
    int NBs  = (Ntot + 255) / 256;        // scan chunks; == K since NBIN=256
    int sh_blocks = (N + 15) / 16;        // score_hist grid

    // ws layout (4B units):
    // [a_src N][a_dst N][moffs Ntot+1][bsum NBs][gbase K+1][pad][pay][xh]
    float* a_src  = (float*)d_ws;
    float* a_dst  = a_src + N;
    int*   moffs  = (int*)(a_dst + N);
    int*   bsum   = moffs + Ntot + 1;
    int*   gbase  = bsum + NBs;
    size_t head_bytes = ((size_t)(2 * N) + (size_t)Ntot + 1 + (size_t)NBs +
                         (size_t)(K + 1)) * 4;
    size_t pay_off = (head_bytes + 15) & ~(size_t)15;
    ull* pay = (ull*)((char*)d_ws + pay_off);
    size_t xh_off = pay_off + (size_t)E * 8;
    __half* xh = (__half*)((char*)d_ws + xh_off);
    size_t need = xh_off + (size_t)N * DIM * 2;

    if (ws_size < need || K > KMAX || K < 1 || NBs != K || NBs > 512 ||
        sh_blocks < NBIN || (N * DIM) % 2 != 0) {
        // fallback: known-good atomic path
        int score_blocks = (N + 3) / 4;
        score_only_kernel<<<score_blocks, 256, 0, stream>>>(x, w_src, w_dst,
                                                            a_src, a_dst, N);
        int ob = (out_size + 255) / 256;
        zero_h_kernel<<<ob, 256, 0, stream>>>(h, out_size);
        int edge_blocks = (E + 3) / 4;
        edge_kernel_atomic<<<edge_blocks, 256, 0, stream>>>(x, ew, src, dst,
                                                            a_src, a_dst, h, E);
        return;
    }

    score_hist_kernel<<<sh_blocks, 256, 0, stream>>>(x, w_src, w_dst, dst,
                                                     a_src, a_dst, xh, moffs,
                                                     N, E, K);
    scan_part<<<NBs, 256, 0, stream>>>(moffs, moffs, bsum, Ntot);
    binpass_kernel<<<NBIN, 1024, 0, stream>>>(ew, src, dst, a_src, a_dst,
                                              moffs, bsum, gbase, pay,
                                              E, N, K, NBs);
    sort_gather_kernel<<<K, 1024, 0, stream>>>(xh, x, pay, gbase,
                                               h, N, K, E);
}